// Round 5
// baseline (49.799 us; speedup 1.0000x reference)
//
#include <hip/hip_runtime.h>
#include <math.h>

#define HH 256
#define WW 256
#define CC 32
#define NN 4
#define QROWS 64                 // rows per block (quarter plane)
#define NBLK (NN * CC * 4)       // 512 blocks

// One fused kernel, 512 blocks x 256 threads (2 blocks/CU: co-residency
// guaranteed without cooperative launch). Block = (plane, quarter).
// Phase 1: pool own 64 rows -> release-store raw sum to partials[bid].
// Sync:    spin until this batch's 128 partials != 0xAA poison (re-poisoned
//          by a 2KB memset at the head of the graph each call).
// Phase 2: filter taps + 3x3 stencil on the SAME 64 rows (still in this
//          XCD's L2) + affine combine, write out.
__global__ __launch_bounds__(256) void fused_dynfilt(
    const float* __restrict__ x,
    const float* __restrict__ conv_w,
    const float* __restrict__ bn_gamma, const float* __restrict__ bn_beta,
    const float* __restrict__ bn_mean, const float* __restrict__ bn_var,
    const float* __restrict__ lamb_l, const float* __restrict__ lamb_h,
    const float* __restrict__ inside_all,
    float* __restrict__ partials,
    float* __restrict__ out)
{
    const int bid   = blockIdx.x;        // plane*4 + q
    const int plane = bid >> 2;
    const int q     = bid & 3;
    const int n = plane >> 5;
    const int c = plane & 31;
    const int g = c >> 2;
    const int t = threadIdx.x;
    const int lane = t & 63;
    const int w = t >> 6;

    const float* xp = x + (size_t)plane * HH * WW;

    // ---------------- phase 1: pool rows [q*64, q*64+64) ----------------------
    {
        const float4* xb = (const float4*)(xp + (size_t)q * QROWS * WW);
        float s = 0.f;
        #pragma unroll
        for (int k = 0; k < 16; ++k) {   // 4096 float4 / 256 threads
            const float4 v = xb[k * 256 + t];
            s += (v.x + v.y) + (v.z + v.w);
        }
        #pragma unroll
        for (int off = 32; off > 0; off >>= 1) s += __shfl_down(s, off, 64);
        __shared__ float wsum[4];
        if (lane == 0) wsum[w] = s;
        __syncthreads();
        if (t == 0) {
            const float tot = (wsum[0] + wsum[1]) + (wsum[2] + wsum[3]);
            __hip_atomic_store((unsigned int*)partials + bid, __float_as_uint(tot),
                               __ATOMIC_RELEASE, __HIP_MEMORY_SCOPE_AGENT);
        }
    }

    // ---------------- sync: wait for this batch's 128 partials ----------------
    __shared__ float sraw[128];
    __shared__ float spooled[CC];
    __shared__ float sfilt[9];
    __shared__ float scoef[3];

    if (t < 128) {
        const unsigned int* pp = (const unsigned int*)partials + n * 128 + t;
        unsigned int bits;
        for (;;) {
            bits = __hip_atomic_load(pp, __ATOMIC_ACQUIRE, __HIP_MEMORY_SCOPE_AGENT);
            if (bits != 0xAAAAAAAAu) break;
            __builtin_amdgcn_s_sleep(2);
        }
        sraw[t] = __uint_as_float(bits);
    }
    __syncthreads();

    if (t < CC)
        spooled[t] = (sraw[4*t] + sraw[4*t+1] + sraw[4*t+2] + sraw[4*t+3])
                   * (1.0f / (HH * WW));
    __syncthreads();

    // ---------------- filter taps + affine coefs ------------------------------
    if (t < 9) {
        const int j = g * 9 + t;
        const float4* wrow = (const float4*)(conv_w + (size_t)j * CC);
        float f = 0.f;
        #pragma unroll
        for (int k = 0; k < 8; ++k) {
            const float4 wv = wrow[k];
            f += spooled[4*k]   * wv.x + spooled[4*k+1] * wv.y
               + spooled[4*k+2] * wv.z + spooled[4*k+3] * wv.w;
        }
        f = (f - bn_mean[j]) * bn_gamma[j] * rsqrtf(bn_var[j] + 1e-5f) + bn_beta[j];
        sfilt[t] = tanhf(f);
    } else if (t == 9) {
        const float ia = inside_all[c];
        const float ll = lamb_l[c];
        scoef[0] = (ia + 1.0f) * ll;              // cA
        scoef[1] = -ia * spooled[c] * ll;         // cB
        scoef[2] = lamb_h[c] + 1.0f;              // cC
    }
    __syncthreads();

    const float f0 = sfilt[0], f1 = sfilt[1], f2 = sfilt[2];
    const float f3 = sfilt[3], f4 = sfilt[4], f5 = sfilt[5];
    const float f6 = sfilt[6], f7 = sfilt[7], f8 = sfilt[8];
    const float cA = scoef[0], cB = scoef[1], cC = scoef[2];

    // ---------------- phase 2: stencil on the same 64 rows --------------------
    #pragma unroll
    for (int e2 = 0; e2 < 2; ++e2) {
        const int row0 = q * QROWS + e2 * 32 + w * 8;

        float4 v[10];
        #pragma unroll
        for (int i = 0; i < 10; ++i) {
            int gr = row0 - 1 + i;
            gr = (gr < 0) ? -gr : ((gr >= HH) ? (2 * HH - 2 - gr) : gr);
            v[i] = *(const float4*)(xp + (size_t)gr * WW + lane * 4);
        }

        float lf[10], rf[10];
        #pragma unroll
        for (int i = 0; i < 10; ++i) {
            lf[i] = __shfl_up(v[i].w, 1, 64);
            if (lane == 0) lf[i] = v[i].y;       // col -1 -> col 1
            rf[i] = __shfl_down(v[i].x, 1, 64);
            if (lane == 63) rf[i] = v[i].z;      // col 256 -> col 254
        }

        float* op = out + (size_t)plane * HH * WW + (size_t)row0 * WW + lane * 4;

        #pragma unroll
        for (int rr = 0; rr < 8; ++rr) {
            const float4 a = v[rr], b = v[rr + 1], cv = v[rr + 2];
            const float al = lf[rr], bl = lf[rr + 1], cl = lf[rr + 2];
            const float ar = rf[rr], br = rf[rr + 1], cr = rf[rr + 2];

            const float s0 = f0*al  + f1*a.x + f2*a.y + f3*bl  + f4*b.x + f5*b.y + f6*cl   + f7*cv.x + f8*cv.y;
            const float s1 = f0*a.x + f1*a.y + f2*a.z + f3*b.x + f4*b.y + f5*b.z + f6*cv.x + f7*cv.y + f8*cv.z;
            const float s2 = f0*a.y + f1*a.z + f2*a.w + f3*b.y + f4*b.z + f5*b.w + f6*cv.y + f7*cv.z + f8*cv.w;
            const float s3 = f0*a.z + f1*a.w + f2*ar  + f3*b.z + f4*b.w + f5*br  + f6*cv.z + f7*cv.w + f8*cr;

            float4 o;
            o.x = cA * s0 + cB + cC * b.x;
            o.y = cA * s1 + cB + cC * b.y;
            o.z = cA * s2 + cB + cC * b.z;
            o.w = cA * s3 + cB + cC * b.w;
            *(float4*)(op + (size_t)rr * WW) = o;
        }
    }
}

extern "C" void kernel_launch(void* const* d_in, const int* in_sizes, int n_in,
                              void* d_out, int out_size, void* d_ws, size_t ws_size,
                              hipStream_t stream) {
    const float* x          = (const float*)d_in[0];
    const float* conv_w     = (const float*)d_in[1];
    const float* bn_gamma   = (const float*)d_in[2];
    const float* bn_beta    = (const float*)d_in[3];
    const float* bn_mean    = (const float*)d_in[4];
    const float* bn_var     = (const float*)d_in[5];
    const float* lamb_l     = (const float*)d_in[6];
    const float* lamb_h     = (const float*)d_in[7];
    const float* inside_all = (const float*)d_in[8];
    float* out      = (float*)d_out;
    float* partials = (float*)d_ws;   // NBLK floats (2 KB)

    // Re-poison the partials region every call so the data-as-flag spin is
    // deterministic (harness only poisons d_ws once, before timing).
    hipMemsetAsync(d_ws, 0xAA, NBLK * sizeof(float), stream);

    hipLaunchKernelGGL(fused_dynfilt, dim3(NBLK), dim3(256), 0, stream,
                       x, conv_w, bn_gamma, bn_beta, bn_mean, bn_var,
                       lamb_l, lamb_h, inside_all, partials, out);
}

// Round 6
// 34.045 us; speedup vs baseline: 1.4627x; 1.4627x over previous
//
#include <hip/hip_runtime.h>
#include <math.h>

#define HH 256
#define WW 256
#define CC 32
#define NN 4
#define NBLK (NN * CC * 8)       // 1024 blocks, block = plane*8 + e (32 rows)

// One fused kernel, 1024 blocks x 256 threads (4 blocks/CU co-resident:
// 36 VGPR, 2KB LDS -> no cooperative launch needed).
// Phase 1: pool own 32 rows -> RELAXED agent store of raw sum (data-as-flag;
//          the word itself is the payload, so no acquire/release needed and
//          no cache invalidate/writeback in the spin).
// Sync:    spin with RELAXED agent loads until this batch's 256 partials
//          != 0xAA poison (4KB re-poisoned by memsetAsync each call).
// Phase 2: filter taps + 3x3 stencil on the same 32 rows + affine, write out.
__global__ __launch_bounds__(256) void fused_dynfilt(
    const float* __restrict__ x,
    const float* __restrict__ conv_w,
    const float* __restrict__ bn_gamma, const float* __restrict__ bn_beta,
    const float* __restrict__ bn_mean, const float* __restrict__ bn_var,
    const float* __restrict__ lamb_l, const float* __restrict__ lamb_h,
    const float* __restrict__ inside_all,
    float* __restrict__ partials,
    float* __restrict__ out)
{
    const int bid   = blockIdx.x;        // plane*8 + e
    const int plane = bid >> 3;
    const int e     = bid & 7;
    const int n = plane >> 5;
    const int c = plane & 31;
    const int g = c >> 2;
    const int t = threadIdx.x;
    const int lane = t & 63;
    const int w = t >> 6;

    const float* xp = x + (size_t)plane * HH * WW;

    // ---------------- phase 1: pool rows [e*32, e*32+32) ----------------------
    {
        const float4* xb = (const float4*)(xp + (size_t)e * 32 * WW);
        float s = 0.f;
        #pragma unroll
        for (int k = 0; k < 8; ++k) {    // 2048 float4 / 256 threads
            const float4 v = xb[k * 256 + t];
            s += (v.x + v.y) + (v.z + v.w);
        }
        #pragma unroll
        for (int off = 32; off > 0; off >>= 1) s += __shfl_down(s, off, 64);
        __shared__ float wsum[4];
        if (lane == 0) wsum[w] = s;
        __syncthreads();
        if (t == 0) {
            const float tot = (wsum[0] + wsum[1]) + (wsum[2] + wsum[3]);
            __hip_atomic_store((unsigned int*)partials + bid, __float_as_uint(tot),
                               __ATOMIC_RELAXED, __HIP_MEMORY_SCOPE_AGENT);
        }
    }

    // ---------------- sync: poll this batch's 256 partials (relaxed) ----------
    __shared__ float sraw[256];
    __shared__ float spooled[CC];
    __shared__ float sfilt[9];
    __shared__ float scoef[3];

    {
        const unsigned int* pp = (const unsigned int*)partials + n * 256 + t;
        unsigned int bits;
        for (;;) {
            bits = __hip_atomic_load(pp, __ATOMIC_RELAXED, __HIP_MEMORY_SCOPE_AGENT);
            if (bits != 0xAAAAAAAAu) break;
            __builtin_amdgcn_s_sleep(2);
        }
        sraw[t] = __uint_as_float(bits);   // sraw[c*8 + e]
    }
    __syncthreads();

    if (t < CC) {
        const float* sr = sraw + t * 8;
        spooled[t] = (((sr[0] + sr[1]) + (sr[2] + sr[3]))
                    + ((sr[4] + sr[5]) + (sr[6] + sr[7]))) * (1.0f / (HH * WW));
    }
    __syncthreads();

    // ---------------- filter taps + affine coefs ------------------------------
    if (t < 9) {
        const int j = g * 9 + t;
        const float4* wrow = (const float4*)(conv_w + (size_t)j * CC);
        float f = 0.f;
        #pragma unroll
        for (int k = 0; k < 8; ++k) {
            const float4 wv = wrow[k];
            f += spooled[4*k]   * wv.x + spooled[4*k+1] * wv.y
               + spooled[4*k+2] * wv.z + spooled[4*k+3] * wv.w;
        }
        f = (f - bn_mean[j]) * bn_gamma[j] * rsqrtf(bn_var[j] + 1e-5f) + bn_beta[j];
        sfilt[t] = tanhf(f);
    } else if (t == 9) {
        const float ia = inside_all[c];
        const float ll = lamb_l[c];
        scoef[0] = (ia + 1.0f) * ll;              // cA
        scoef[1] = -ia * spooled[c] * ll;         // cB
        scoef[2] = lamb_h[c] + 1.0f;              // cC
    }
    __syncthreads();

    const float f0 = sfilt[0], f1 = sfilt[1], f2 = sfilt[2];
    const float f3 = sfilt[3], f4 = sfilt[4], f5 = sfilt[5];
    const float f6 = sfilt[6], f7 = sfilt[7], f8 = sfilt[8];
    const float cA = scoef[0], cB = scoef[1], cC = scoef[2];

    // ---------------- phase 2: stencil on the same 32 rows --------------------
    const int row0 = e * 32 + w * 8;

    float4 v[10];
    #pragma unroll
    for (int i = 0; i < 10; ++i) {
        int gr = row0 - 1 + i;
        gr = (gr < 0) ? -gr : ((gr >= HH) ? (2 * HH - 2 - gr) : gr);
        v[i] = *(const float4*)(xp + (size_t)gr * WW + lane * 4);
    }

    float lf[10], rf[10];
    #pragma unroll
    for (int i = 0; i < 10; ++i) {
        lf[i] = __shfl_up(v[i].w, 1, 64);
        if (lane == 0) lf[i] = v[i].y;       // col -1 -> col 1
        rf[i] = __shfl_down(v[i].x, 1, 64);
        if (lane == 63) rf[i] = v[i].z;      // col 256 -> col 254
    }

    float* op = out + (size_t)plane * HH * WW + (size_t)row0 * WW + lane * 4;

    #pragma unroll
    for (int rr = 0; rr < 8; ++rr) {
        const float4 a = v[rr], b = v[rr + 1], cv = v[rr + 2];
        const float al = lf[rr], bl = lf[rr + 1], cl = lf[rr + 2];
        const float ar = rf[rr], br = rf[rr + 1], cr = rf[rr + 2];

        const float s0 = f0*al  + f1*a.x + f2*a.y + f3*bl  + f4*b.x + f5*b.y + f6*cl   + f7*cv.x + f8*cv.y;
        const float s1 = f0*a.x + f1*a.y + f2*a.z + f3*b.x + f4*b.y + f5*b.z + f6*cv.x + f7*cv.y + f8*cv.z;
        const float s2 = f0*a.y + f1*a.z + f2*a.w + f3*b.y + f4*b.z + f5*b.w + f6*cv.y + f7*cv.z + f8*cv.w;
        const float s3 = f0*a.z + f1*a.w + f2*ar  + f3*b.z + f4*b.w + f5*br  + f6*cv.z + f7*cv.w + f8*cr;

        float4 o;
        o.x = cA * s0 + cB + cC * b.x;
        o.y = cA * s1 + cB + cC * b.y;
        o.z = cA * s2 + cB + cC * b.z;
        o.w = cA * s3 + cB + cC * b.w;
        *(float4*)(op + (size_t)rr * WW) = o;
    }
}

extern "C" void kernel_launch(void* const* d_in, const int* in_sizes, int n_in,
                              void* d_out, int out_size, void* d_ws, size_t ws_size,
                              hipStream_t stream) {
    const float* x          = (const float*)d_in[0];
    const float* conv_w     = (const float*)d_in[1];
    const float* bn_gamma   = (const float*)d_in[2];
    const float* bn_beta    = (const float*)d_in[3];
    const float* bn_mean    = (const float*)d_in[4];
    const float* bn_var     = (const float*)d_in[5];
    const float* lamb_l     = (const float*)d_in[6];
    const float* lamb_h     = (const float*)d_in[7];
    const float* inside_all = (const float*)d_in[8];
    float* out      = (float*)d_out;
    float* partials = (float*)d_ws;   // NBLK floats (4 KB)

    // Re-poison the flag region each call (data-as-flag spin needs it).
    hipMemsetAsync(d_ws, 0xAA, NBLK * sizeof(float), stream);

    hipLaunchKernelGGL(fused_dynfilt, dim3(NBLK), dim3(256), 0, stream,
                       x, conv_w, bn_gamma, bn_beta, bn_mean, bn_var,
                       lamb_l, lamb_h, inside_all, partials, out);
}